// Round 1
// baseline (885.669 us; speedup 1.0000x reference)
//
#include <hip/hip_runtime.h>
#include <hip/hip_bf16.h>

#define LQ 300
#define NB 32
#define SK 1024
#define EE 256
#define HH 8
#define DH 32
#define BH 256   // N*H
#define LPAD 304
#define NLT 19   // ceil(300/16)

typedef __attribute__((ext_vector_type(8))) short short8;
typedef __attribute__((ext_vector_type(4))) float f32x4;

#define MFMA16(a, b, c) __builtin_amdgcn_mfma_f32_16x16x32_bf16((a), (b), (c), 0, 0, 0)

__device__ __forceinline__ short f2bf(float f) {
    unsigned u = __float_as_uint(f);
    u += 0x7FFFu + ((u >> 16) & 1u);   // round-to-nearest-even
    return (short)(u >> 16);
}

__device__ __forceinline__ short8 cvt8(const float* __restrict__ p) {
    float4 x = *(const float4*)p;
    float4 y = *(const float4*)(p + 4);
    short8 r;
    r[0] = f2bf(x.x); r[1] = f2bf(x.y); r[2] = f2bf(x.z); r[3] = f2bf(x.w);
    r[4] = f2bf(y.x); r[5] = f2bf(y.y); r[6] = f2bf(y.z); r[7] = f2bf(y.w);
    return r;
}

// ---------------------------------------------------------------------------
// QKV projection: C[t, e] = X[t,:] @ W[e,:]^T + bias  (q scaled), bf16 out
// wave tile: 16 tokens x 64 features. Units: q 600*4, k 2048*4, v 2048*4.
// ---------------------------------------------------------------------------
__global__ __launch_bounds__(256) void proj_kernel(
    const float* __restrict__ query, const float* __restrict__ key,
    const float* __restrict__ value, const float* __restrict__ w,
    const float* __restrict__ bias,
    short* __restrict__ qws, short* __restrict__ kws, short* __restrict__ vws)
{
    int wave = (blockIdx.x * 256 + threadIdx.x) >> 6;
    int lid = threadIdx.x & 63;
    int quad = lid >> 4, l16 = lid & 15;

    const int UQ = 600 * 4, UK = 2048 * 4;
    int u = wave, p;
    const float* X;
    if (u < UQ)            { p = 0; X = query; }
    else if (u < UQ + UK)  { p = 1; X = key;   u -= UQ; }
    else                   { p = 2; X = value; u -= UQ + UK; }
    int ft = u & 3, tt = u >> 2;
    int t = tt * 16 + l16;

    const float* wbase = w + (size_t)p * EE * EE;
    f32x4 acc[4];
    #pragma unroll
    for (int f = 0; f < 4; f++) acc[f] = (f32x4){0.f, 0.f, 0.f, 0.f};

    #pragma unroll
    for (int ks = 0; ks < 8; ks++) {
        short8 af = cvt8(X + (size_t)t * EE + ks * 32 + quad * 8);
        #pragma unroll
        for (int f = 0; f < 4; f++) {
            short8 bf = cvt8(wbase + (size_t)(ft * 64 + f * 16 + l16) * EE + ks * 32 + quad * 8);
            acc[f] = MFMA16(af, bf, acc[f]);
        }
    }

    // epilogue: row = token tt*16 + quad*4 + r, col = feature ft*64 + f*16 + l16
    #pragma unroll
    for (int f = 0; f < 4; f++) {
        int feat = ft * 64 + f * 16 + l16;
        float bia = bias[p * EE + feat];
        int h = feat >> 5, d = feat & 31;
        #pragma unroll
        for (int r = 0; r < 4; r++) {
            int tok = tt * 16 + quad * 4 + r;
            float v = acc[f][r] + bia;
            int n = tok & 31;
            int b = n * HH + h;
            if (p == 0) {
                v *= 0.17677669529663687f;           // Dh^-0.5
                int l = tok >> 5;
                qws[((size_t)b * LPAD + l) * DH + d] = f2bf(v);
            } else if (p == 1) {
                int s = tok >> 5;
                kws[((size_t)b * SK + s) * DH + d] = f2bf(v);
            } else {
                int s = tok >> 5;
                vws[((size_t)b * SK + s) * DH + d] = f2bf(v);
            }
        }
    }
}

// ---------------------------------------------------------------------------
// Fused flash attention: one wave per (b, 16-row L-tile); online softmax,
// gaussian added fp32 in C-layout, P via LDS round-trip to A-layout.
// ---------------------------------------------------------------------------
__global__ __launch_bounds__(256) void attn_kernel(
    const short* __restrict__ qws, const short* __restrict__ kws,
    const short* __restrict__ vws, const float* __restrict__ gauss,
    const unsigned char* __restrict__ mask,
    short* __restrict__ ows)
{
    __shared__ short pbuf[4][16 * 40];   // per-wave P tile, stride 40 ushorts (16B-aligned rows)
    int wv = threadIdx.x >> 6;
    int wave = blockIdx.x * 4 + wv;
    int b = wave / NLT, lt = wave % NLT;
    int lid = threadIdx.x & 63, quad = lid >> 4, l16 = lid & 15;
    int n = b >> 3, h = b & 7;

    // Q A-fragment: A[m=lane&15=l][k=quad*8+j=d]
    int ql = lt * 16 + l16;
    short8 qa = *(const short8*)(qws + ((size_t)b * LPAD + ql) * DH + quad * 8);

    f32x4 o0 = {0.f, 0.f, 0.f, 0.f}, o1 = {0.f, 0.f, 0.f, 0.f};
    float m[4]    = {-3e38f, -3e38f, -3e38f, -3e38f};
    float lsum[4] = {0.f, 0.f, 0.f, 0.f};
    const float* gbase = gauss + (size_t)b * LQ * SK;
    short* pb = pbuf[wv];

    for (int sc0 = 0; sc0 < SK; sc0 += 32) {
        // K B-fragments (BT layout = k[b][s][d]): lane reads 8 consecutive d at s
        short8 kb0 = *(const short8*)(kws + ((size_t)b * SK + sc0 + l16) * DH + quad * 8);
        short8 kb1 = *(const short8*)(kws + ((size_t)b * SK + sc0 + 16 + l16) * DH + quad * 8);
        // V B-fragments (BT = v^T[d][s]): lane needs v[s=sc0+quad*8+j][d=t*16+l16]
        short8 vb0, vb1;
        #pragma unroll
        for (int j = 0; j < 8; j++) {
            size_t vr = ((size_t)b * SK + sc0 + quad * 8 + j) * DH;
            vb0[j] = vws[vr + l16];
            vb1[j] = vws[vr + 16 + l16];
        }

        f32x4 z = {0.f, 0.f, 0.f, 0.f};
        f32x4 c0 = MFMA16(qa, kb0, z);
        f32x4 c1 = MFMA16(qa, kb1, z);

        unsigned char mk0 = mask[n * SK + sc0 + l16];
        unsigned char mk1 = mask[n * SK + sc0 + 16 + l16];

        float s0v[4], s1v[4];
        #pragma unroll
        for (int r = 0; r < 4; r++) {
            int l = lt * 16 + quad * 4 + r;
            int lc = l < LQ ? l : LQ - 1;        // clamp: avoid OOB on tail tile
            const float* gr = gbase + (size_t)lc * SK + sc0;
            s0v[r] = mk0 ? -3e38f : (c0[r] + gr[l16]);
            s1v[r] = mk1 ? -3e38f : (c1[r] + gr[16 + l16]);
        }

        #pragma unroll
        for (int r = 0; r < 4; r++) {
            float mx = fmaxf(s0v[r], s1v[r]);
            #pragma unroll
            for (int i = 1; i < 16; i <<= 1) mx = fmaxf(mx, __shfl_xor(mx, i, 64));
            float nm = fmaxf(m[r], mx);
            float alpha = __expf(m[r] - nm);
            float p0 = __expf(s0v[r] - nm);
            float p1 = __expf(s1v[r] - nm);
            s0v[r] = p0; s1v[r] = p1;
            float sm = p0 + p1;
            #pragma unroll
            for (int i = 1; i < 16; i <<= 1) sm += __shfl_xor(sm, i, 64);
            lsum[r] = lsum[r] * alpha + sm;
            m[r] = nm;
            o0[r] *= alpha; o1[r] *= alpha;
        }

        // P (C-layout) -> LDS -> A-layout fragment
        #pragma unroll
        for (int r = 0; r < 4; r++) {
            int row = quad * 4 + r;
            pb[row * 40 + l16]      = f2bf(s0v[r]);
            pb[row * 40 + 16 + l16] = f2bf(s1v[r]);
        }
        short8 pa = *(const short8*)(pb + l16 * 40 + quad * 8);

        o0 = MFMA16(pa, vb0, o0);
        o1 = MFMA16(pa, vb1, o1);
    }

    // epilogue: write attn output token-major bf16 [l*N+n][h*32 + d]
    #pragma unroll
    for (int r = 0; r < 4; r++) {
        int l = lt * 16 + quad * 4 + r;
        if (l < LQ) {
            float inv = 1.0f / lsum[r];
            size_t base = ((size_t)l * NB + n) * EE + h * DH;
            ows[base + l16]      = f2bf(o0[r] * inv);
            ows[base + 16 + l16] = f2bf(o1[r] * inv);
        }
    }
}

// ---------------------------------------------------------------------------
// Output projection: out[t,e] = X[t,:] @ Wout[e,:]^T + bias, fp32 out
// ---------------------------------------------------------------------------
__global__ __launch_bounds__(256) void oproj_kernel(
    const short* __restrict__ xa, const float* __restrict__ w,
    const float* __restrict__ bias, float* __restrict__ out)
{
    int wave = (blockIdx.x * 256 + threadIdx.x) >> 6;
    int lid = threadIdx.x & 63, quad = lid >> 4, l16 = lid & 15;
    int ft = wave & 3, tt = wave >> 2;
    int t = tt * 16 + l16;

    f32x4 acc[4];
    #pragma unroll
    for (int f = 0; f < 4; f++) acc[f] = (f32x4){0.f, 0.f, 0.f, 0.f};

    #pragma unroll
    for (int ks = 0; ks < 8; ks++) {
        short8 af = *(const short8*)(xa + (size_t)t * EE + ks * 32 + quad * 8);
        #pragma unroll
        for (int f = 0; f < 4; f++) {
            short8 bf = cvt8(w + (size_t)(ft * 64 + f * 16 + l16) * EE + ks * 32 + quad * 8);
            acc[f] = MFMA16(af, bf, acc[f]);
        }
    }

    #pragma unroll
    for (int f = 0; f < 4; f++) {
        int e = ft * 64 + f * 16 + l16;
        float bi = bias[e];
        #pragma unroll
        for (int r = 0; r < 4; r++) {
            int tok = tt * 16 + quad * 4 + r;
            out[(size_t)tok * EE + e] = acc[f][r] + bi;
        }
    }
}

extern "C" void kernel_launch(void* const* d_in, const int* in_sizes, int n_in,
                              void* d_out, int out_size, void* d_ws, size_t ws_size,
                              hipStream_t stream) {
    const float* query = (const float*)d_in[0];
    const float* key   = (const float*)d_in[1];
    const float* value = (const float*)d_in[2];
    const float* gauss = (const float*)d_in[3];
    const unsigned char* mask = (const unsigned char*)d_in[4];
    const float* ipw = (const float*)d_in[5];
    const float* ipb = (const float*)d_in[6];
    const float* opw = (const float*)d_in[7];
    const float* opb = (const float*)d_in[8];
    float* out = (float*)d_out;

    short* qws = (short*)d_ws;                         // 256*304*32
    short* kws = qws + (size_t)BH * LPAD * DH;         // 256*1024*32
    short* vws = kws + (size_t)BH * SK * DH;           // 256*1024*32
    short* ows = vws + (size_t)BH * SK * DH;           // 9600*256

    proj_kernel<<<4696, 256, 0, stream>>>(query, key, value, ipw, ipb, qws, kws, vws);
    attn_kernel<<<1216, 256, 0, stream>>>(qws, kws, vws, gauss, mask, ows);
    oproj_kernel<<<600, 256, 0, stream>>>(ows, opw, opb, out);
}

// Round 2
// 593.461 us; speedup vs baseline: 1.4924x; 1.4924x over previous
//
#include <hip/hip_runtime.h>

#define LQ 300
#define NB 32
#define SK 1024
#define EE 256
#define HH 8
#define DH 32
#define BH 256   // N*H
#define LPAD 304
#define NLT 19   // ceil(300/16)

typedef short short8 __attribute__((ext_vector_type(8)));
typedef short short4v __attribute__((ext_vector_type(4)));
typedef float f32x4 __attribute__((ext_vector_type(4)));

#define MFMA16(a, b, c) __builtin_amdgcn_mfma_f32_16x16x32_bf16((a), (b), (c), 0, 0, 0)

__device__ __forceinline__ short f2bf(float f) {
    unsigned u = __float_as_uint(f);
    u += 0x7FFFu + ((u >> 16) & 1u);   // round-to-nearest-even
    return (short)(u >> 16);
}

__device__ __forceinline__ short8 cvt8(const float* __restrict__ p) {
    float4 x = *(const float4*)p;
    float4 y = *(const float4*)(p + 4);
    short8 r;
    r[0] = f2bf(x.x); r[1] = f2bf(x.y); r[2] = f2bf(x.z); r[3] = f2bf(x.w);
    r[4] = f2bf(y.x); r[5] = f2bf(y.y); r[6] = f2bf(y.z); r[7] = f2bf(y.w);
    return r;
}

// ---------------------------------------------------------------------------
// prep: convert in_proj_weight (3E x E) + out_proj_weight (E x E) to bf16
// ---------------------------------------------------------------------------
__global__ __launch_bounds__(256) void prep_kernel(
    const float* __restrict__ ipw, const float* __restrict__ opw,
    short* __restrict__ wbf)
{
    int i = blockIdx.x * 256 + threadIdx.x;   // 0..65535
    int base = i * 4;
    const float* src = (base < 3 * EE * EE) ? (ipw + base) : (opw + base - 3 * EE * EE);
    float4 x = *(const float4*)src;
    short4v r;
    r[0] = f2bf(x.x); r[1] = f2bf(x.y); r[2] = f2bf(x.z); r[3] = f2bf(x.w);
    *(short4v*)(wbf + base) = r;
}

// ---------------------------------------------------------------------------
// QKV projection: wave = 16 tokens x ALL 256 features, K=256. X read once.
// ---------------------------------------------------------------------------
__global__ __launch_bounds__(256) void proj_kernel(
    const float* __restrict__ query, const float* __restrict__ key,
    const float* __restrict__ value, const short* __restrict__ wbf,
    const float* __restrict__ bias,
    short* __restrict__ qws, short* __restrict__ kws, short* __restrict__ vws)
{
    int wave = (blockIdx.x * 256 + threadIdx.x) >> 6;
    int lid = threadIdx.x & 63, quad = lid >> 4, l16 = lid & 15;

    int u = wave, p;
    const float* X;
    if (u < 600)             { p = 0; X = query; }
    else if (u < 600 + 2048) { p = 1; X = key;   u -= 600; }
    else                     { p = 2; X = value; u -= 2648; }
    int t = u * 16 + l16;

    const short* wb = wbf + p * EE * EE;
    f32x4 acc[16];
    #pragma unroll
    for (int f = 0; f < 16; f++) acc[f] = (f32x4){0.f, 0.f, 0.f, 0.f};

    for (int ks = 0; ks < 8; ks++) {
        short8 af = cvt8(X + (size_t)t * EE + ks * 32 + quad * 8);
        #pragma unroll
        for (int f = 0; f < 16; f++) {
            short8 bf = *(const short8*)(wb + (size_t)(f * 16 + l16) * EE + ks * 32 + quad * 8);
            acc[f] = MFMA16(af, bf, acc[f]);
        }
    }

    int tokbase = (wave < 600 ? wave : u) * 16;   // token group base within its matrix
    #pragma unroll
    for (int f = 0; f < 16; f++) {
        int feat = f * 16 + l16;
        float bia = bias[p * EE + feat];
        int h = feat >> 5, d = feat & 31;
        #pragma unroll
        for (int r = 0; r < 4; r++) {
            int tok = tokbase + quad * 4 + r;
            float v = acc[f][r] + bia;
            int n = tok & 31, s = tok >> 5;
            int b = n * HH + h;
            if (p == 0) {
                v *= 0.17677669529663687f;   // Dh^-0.5
                qws[((size_t)b * LPAD + s) * DH + d] = f2bf(v);
            } else if (p == 1) {
                kws[((size_t)b * SK + s) * DH + d] = f2bf(v);
            } else {
                vws[((size_t)b * SK + s) * DH + d] = f2bf(v);
            }
        }
    }
}

// ---------------------------------------------------------------------------
// V transpose: vt[b][d][s] from vws[b][s][d], LDS tiled, coalesced both sides
// ---------------------------------------------------------------------------
__global__ __launch_bounds__(256) void vtrans_kernel(
    const short* __restrict__ vws, short* __restrict__ vt)
{
    __shared__ __align__(16) short tile[32][272];   // 272: 16B-aligned rows
    int b = blockIdx.x >> 2, s0 = (blockIdx.x & 3) * 256;
    const short* src = vws + ((size_t)b * SK + s0) * DH;
    #pragma unroll
    for (int pass = 0; pass < 4; pass++) {
        int i = pass * 256 + threadIdx.x;
        int sl = i >> 2, d0 = (i & 3) * 8;
        short8 x = *(const short8*)(src + sl * DH + d0);
        #pragma unroll
        for (int j = 0; j < 8; j++) tile[d0 + j][sl] = x[j];
    }
    __syncthreads();
    short* dst = vt + (size_t)b * DH * SK + s0;
    #pragma unroll
    for (int pass = 0; pass < 4; pass++) {
        int i = pass * 256 + threadIdx.x;
        int d = i >> 5, sl0 = (i & 31) * 8;
        *(short8*)(dst + (size_t)d * SK + sl0) = *(const short8*)(&tile[d][sl0]);
    }
}

// ---------------------------------------------------------------------------
// Flash attention: block = (b, 16-row L-tile); 4 waves split S (256 each),
// 64-wide S chunks (4 serial iterations), LDS flash-merge of partials.
// ---------------------------------------------------------------------------
__global__ __launch_bounds__(256) void attn_kernel(
    const short* __restrict__ qws, const short* __restrict__ kws,
    const short* __restrict__ vt, const float* __restrict__ gauss,
    const unsigned char* __restrict__ mask, short* __restrict__ ows)
{
    __shared__ __align__(16) short pbuf[4][16 * 80];   // P tile per wave, swizzled
    __shared__ float obuf[4][16][32];
    __shared__ float mbuf[4][16];
    __shared__ float lbuf[4][16];

    int b = blockIdx.x / NLT, lt = blockIdx.x % NLT;
    int wv = threadIdx.x >> 6;
    int lid = threadIdx.x & 63, quad = lid >> 4, l16 = lid & 15;
    int n = b >> 3, h = b & 7;

    int ql = lt * 16 + l16;
    short8 qa = *(const short8*)(qws + ((size_t)b * LPAD + ql) * DH + quad * 8);

    f32x4 o0 = {0.f, 0.f, 0.f, 0.f}, o1 = {0.f, 0.f, 0.f, 0.f};
    float mr[4] = {-3e38f, -3e38f, -3e38f, -3e38f};
    float ls[4] = {0.f, 0.f, 0.f, 0.f};

    const float* gbase = gauss + (size_t)b * LQ * SK;
    const float* grow[4];
    #pragma unroll
    for (int r = 0; r < 4; r++) {
        int l = lt * 16 + quad * 4 + r;
        grow[r] = gbase + (size_t)(l < LQ ? l : LQ - 1) * SK + l16;
    }

    short* pb = pbuf[wv];
    int sw = quad << 4;               // store-side XOR swizzle key ((row>>2)&3)<<4
    int rw = (l16 >> 2) << 4;         // read-side key
    int sbase = wv * 256;

    for (int it = 0; it < 4; it++) {
        int sc = sbase + it * 64;

        short8 kb[4];
        #pragma unroll
        for (int c = 0; c < 4; c++)
            kb[c] = *(const short8*)(kws + ((size_t)b * SK + sc + c * 16 + l16) * DH + quad * 8);

        short8 vb[2][2];
        #pragma unroll
        for (int t2 = 0; t2 < 2; t2++)
            #pragma unroll
            for (int k2 = 0; k2 < 2; k2++)
                vb[t2][k2] = *(const short8*)(vt + ((size_t)b * DH + t2 * 16 + l16) * SK + sc + k2 * 32 + quad * 8);

        bool mk[4];
        #pragma unroll
        for (int c = 0; c < 4; c++) mk[c] = mask[n * SK + sc + c * 16 + l16] != 0;

        float g[4][4];
        #pragma unroll
        for (int r = 0; r < 4; r++)
            #pragma unroll
            for (int c = 0; c < 4; c++) g[r][c] = grow[r][sc + c * 16];

        f32x4 z = {0.f, 0.f, 0.f, 0.f};
        f32x4 cc[4];
        #pragma unroll
        for (int c = 0; c < 4; c++) cc[c] = MFMA16(qa, kb[c], z);

        float sv[4][4];
        #pragma unroll
        for (int r = 0; r < 4; r++)
            #pragma unroll
            for (int c = 0; c < 4; c++)
                sv[r][c] = mk[c] ? -3e38f : (cc[c][r] + g[r][c]);

        #pragma unroll
        for (int r = 0; r < 4; r++) {
            float mx = fmaxf(fmaxf(sv[r][0], sv[r][1]), fmaxf(sv[r][2], sv[r][3]));
            #pragma unroll
            for (int i = 1; i < 16; i <<= 1) mx = fmaxf(mx, __shfl_xor(mx, i, 64));
            float nm = fmaxf(mr[r], mx);
            float al = __expf(mr[r] - nm);
            float sm = 0.f;
            #pragma unroll
            for (int c = 0; c < 4; c++) { sv[r][c] = __expf(sv[r][c] - nm); sm += sv[r][c]; }
            #pragma unroll
            for (int i = 1; i < 16; i <<= 1) sm += __shfl_xor(sm, i, 64);
            ls[r] = ls[r] * al + sm;
            mr[r] = nm;
            o0[r] *= al; o1[r] *= al;
        }

        // P (C-layout) -> LDS (swizzled) -> A-layout fragments
        #pragma unroll
        for (int r = 0; r < 4; r++) {
            int row = quad * 4 + r;
            #pragma unroll
            for (int c = 0; c < 4; c++)
                pb[row * 80 + ((c * 16 + l16) ^ sw)] = f2bf(sv[r][c]);
        }
        short8 pa0 = *(const short8*)(pb + l16 * 80 + ((0 + quad * 8) ^ rw));
        short8 pa1 = *(const short8*)(pb + l16 * 80 + ((32 + quad * 8) ^ rw));

        o0 = MFMA16(pa0, vb[0][0], o0);
        o0 = MFMA16(pa1, vb[0][1], o0);
        o1 = MFMA16(pa0, vb[1][0], o1);
        o1 = MFMA16(pa1, vb[1][1], o1);
    }

    // write partials
    #pragma unroll
    for (int r = 0; r < 4; r++) {
        int row = quad * 4 + r;
        if (l16 == 0) { mbuf[wv][row] = mr[r]; lbuf[wv][row] = ls[r]; }
        obuf[wv][row][l16] = o0[r];
        obuf[wv][row][16 + l16] = o1[r];
    }
    __syncthreads();

    // flash merge: thread = (row, col)
    int row = threadIdx.x >> 4, col = threadIdx.x & 15;
    float M = -3e38f;
    #pragma unroll
    for (int w = 0; w < 4; w++) M = fmaxf(M, mbuf[w][row]);
    float L = 0.f, a0 = 0.f, a1 = 0.f;
    #pragma unroll
    for (int w = 0; w < 4; w++) {
        float e = __expf(mbuf[w][row] - M);
        L += e * lbuf[w][row];
        a0 += e * obuf[w][row][col];
        a1 += e * obuf[w][row][16 + col];
    }
    int l = lt * 16 + row;
    if (l < LQ) {
        float inv = 1.0f / L;
        size_t base = ((size_t)l * NB + n) * EE + h * DH;
        ows[base + col]      = f2bf(a0 * inv);
        ows[base + 16 + col] = f2bf(a1 * inv);
    }
}

// ---------------------------------------------------------------------------
// Output projection: wave = 16 tokens x 256 features, bf16 A/B, fp32 out
// ---------------------------------------------------------------------------
__global__ __launch_bounds__(256) void oproj_kernel(
    const short* __restrict__ xa, const short* __restrict__ wbf,
    const float* __restrict__ bias, float* __restrict__ out)
{
    int wave = (blockIdx.x * 256 + threadIdx.x) >> 6;
    int lid = threadIdx.x & 63, quad = lid >> 4, l16 = lid & 15;
    int t = wave * 16 + l16;

    const short* wb = wbf + 3 * EE * EE;
    f32x4 acc[16];
    #pragma unroll
    for (int f = 0; f < 16; f++) acc[f] = (f32x4){0.f, 0.f, 0.f, 0.f};

    for (int ks = 0; ks < 8; ks++) {
        short8 af = *(const short8*)(xa + (size_t)t * EE + ks * 32 + quad * 8);
        #pragma unroll
        for (int f = 0; f < 16; f++) {
            short8 bf = *(const short8*)(wb + (size_t)(f * 16 + l16) * EE + ks * 32 + quad * 8);
            acc[f] = MFMA16(af, bf, acc[f]);
        }
    }

    #pragma unroll
    for (int f = 0; f < 16; f++) {
        int e = f * 16 + l16;
        float bi = bias[e];
        #pragma unroll
        for (int r = 0; r < 4; r++) {
            int tok = wave * 16 + quad * 4 + r;
            out[(size_t)tok * EE + e] = acc[f][r] + bi;
        }
    }
}

extern "C" void kernel_launch(void* const* d_in, const int* in_sizes, int n_in,
                              void* d_out, int out_size, void* d_ws, size_t ws_size,
                              hipStream_t stream) {
    const float* query = (const float*)d_in[0];
    const float* key   = (const float*)d_in[1];
    const float* value = (const float*)d_in[2];
    const float* gauss = (const float*)d_in[3];
    const unsigned char* mask = (const unsigned char*)d_in[4];
    const float* ipw = (const float*)d_in[5];
    const float* ipb = (const float*)d_in[6];
    const float* opw = (const float*)d_in[7];
    const float* opb = (const float*)d_in[8];
    float* out = (float*)d_out;

    short* wbf = (short*)d_ws;                        // 262144 shorts
    short* qws = wbf + 4 * EE * EE;                   // 256*304*32
    short* kws = qws + (size_t)BH * LPAD * DH;        // 256*1024*32
    short* vws = kws + (size_t)BH * SK * DH;          // 256*1024*32
    short* vt  = vws + (size_t)BH * SK * DH;          // 256*32*1024
    short* ows = vt  + (size_t)BH * SK * DH;          // 9600*256

    prep_kernel<<<256, 256, 0, stream>>>(ipw, opw, wbf);
    proj_kernel<<<1174, 256, 0, stream>>>(query, key, value, wbf, ipb, qws, kws, vws);
    vtrans_kernel<<<1024, 256, 0, stream>>>(vws, vt);
    attn_kernel<<<BH * NLT, 256, 0, stream>>>(qws, kws, vt, gauss, mask, ows);
    oproj_kernel<<<150, 256, 0, stream>>>(ows, wbf, opb, out);
}